// Round 3
// baseline (168.305 us; speedup 1.0000x reference)
//
#include <hip/hip_runtime.h>

typedef short bf16x8 __attribute__((ext_vector_type(8)));
typedef float floatx4 __attribute__((ext_vector_type(4)));
typedef unsigned short ushort4v __attribute__((ext_vector_type(4)));
typedef unsigned int uintx4 __attribute__((ext_vector_type(4)));
typedef unsigned int uintx2 __attribute__((ext_vector_type(2)));

#define HW 3136
#define WS 100   // attn LDS stride (floats) per pixel

// prep layout (floats)
#define P_CP   0
#define P_W1   4      // 288
#define P_W2   292    // 128
#define P_BN   424    // a1[HW], c1[HW], a2[HW], c2[HW]
#define PREP_FLOATS (424 + 4 * HW)

// ---- bf16 bit helpers (RNE) ----
__device__ __forceinline__ unsigned short f2bf(float f) {
    unsigned int u = __float_as_uint(f);
    unsigned int r = (u + 0x7FFFu + ((u >> 16) & 1u)) >> 16;
    return (unsigned short)r;
}
__device__ __forceinline__ float bf2f(unsigned short u) {
    return __uint_as_float(((unsigned int)u) << 16);
}
__device__ __forceinline__ void unp8(uint4 u, float* o) {
    o[0] = bf2f((unsigned short)(u.x & 0xFFFFu)); o[1] = bf2f((unsigned short)(u.x >> 16));
    o[2] = bf2f((unsigned short)(u.y & 0xFFFFu)); o[3] = bf2f((unsigned short)(u.y >> 16));
    o[4] = bf2f((unsigned short)(u.z & 0xFFFFu)); o[5] = bf2f((unsigned short)(u.z >> 16));
    o[6] = bf2f((unsigned short)(u.w & 0xFFFFu)); o[7] = bf2f((unsigned short)(u.w >> 16));
}
__device__ __forceinline__ float ldp(const void* p, int i, int isb) {
    return isb ? bf2f(((const unsigned short*)p)[i]) : ((const float*)p)[i];
}

// ---------------------------------------------------------------------------
// proj: wave = 64 px x 16 rows over K=256. Block = 384 threads = 6 waves =
// ALL SIX row-tiles (w1,w2,w3[0:16/16:32/32:48/48:64]) of ONE (n, px0).
// Rationale (round-2 post-mortem): the 6 row-tiles read the SAME 64KB
// x-slice and rt0/rt1 co-write the same 64B y12 lines. Round-2 scattered
// these sharers across blocks/XCDs -> FETCH 2.2x (per-XCD L2 copies) and
// WRITE 3.4x (split-line RMW). Keeping them in one block makes x re-reads
// L2-local and y12 lines single-L2.
// Grid = 16n x 49pt = 784 blocks; __launch_bounds__(384,6) -> 4 blocks/CU
// capacity = 1024 >= 784: whole grid co-resident, zero scheduling tail.
// BN prep spread over blocks 0..15. dtype resolved host-side via in_sizes.
// Outputs: y12[n][px][32ch] and y3a[n][k8][px][8ch] (attn-coalesced).
// ---------------------------------------------------------------------------
struct __align__(16) Stage { unsigned int b[16]; bf16x8 a; };

template <int ISB>
__device__ __forceinline__ void ldstage(const void* x, size_t xb,
                                        const void* wp, int arow, int ch, Stage& s)
{
    if (ISB) {
        const unsigned short* p = (const unsigned short*)x + xb + (size_t)ch * HW;
        #pragma unroll
        for (int j = 0; j < 8; ++j)
            *(uintx2*)&s.b[2 * j] = *(const uintx2*)(p + (size_t)j * HW);
        s.a = *(const bf16x8*)((const unsigned short*)wp + arow * 256 + ch);
    } else {
        const float* p = (const float*)x + xb + (size_t)ch * HW;
        #pragma unroll
        for (int j = 0; j < 8; ++j) {
            floatx4 f = *(const floatx4*)(p + (size_t)j * HW);
            s.b[2 * j + 0] = (unsigned)f2bf(f[0]) | ((unsigned)f2bf(f[1]) << 16);
            s.b[2 * j + 1] = (unsigned)f2bf(f[2]) | ((unsigned)f2bf(f[3]) << 16);
        }
        const float* fp = (const float*)wp + arow * 256 + ch;
        bf16x8 a;
        #pragma unroll
        for (int j = 0; j < 8; ++j) a[j] = (short)f2bf(fp[j]);
        s.a = a;
    }
}

__device__ __forceinline__ void domfma(const Stage& s, floatx4 (&acc)[4])
{
    #pragma unroll
    for (int t = 0; t < 4; ++t) {
        const int wi = t >> 1;
        uintx4 uv;
        #pragma unroll
        for (int d = 0; d < 4; ++d) {
            const unsigned lo = s.b[2 * (2 * d) + wi];
            const unsigned hi = s.b[2 * (2 * d + 1) + wi];
            const unsigned v = (t & 1) ? ((lo >> 16) | (hi & 0xFFFF0000u))
                                       : ((lo & 0xFFFFu) | (hi << 16));
            uv[d] = v;
        }
        bf16x8 B = __builtin_bit_cast(bf16x8, uv);
        acc[t] = __builtin_amdgcn_mfma_f32_16x16x32_bf16(s.a, B, acc[t], 0, 0, 0);
    }
}

template <int ISB>
__device__ void proj_body(const void* x, const void* wp, int arow,
                          size_t xb, int quad, floatx4 (&acc)[4])
{
    Stage s0, s1;
    ldstage<ISB>(x, xb, wp, arow, quad * 8, s0);
    #pragma unroll
    for (int q = 0; q < 8; q += 2) {
        ldstage<ISB>(x, xb, wp, arow, (q + 1) * 32 + quad * 8, s1);
        domfma(s0, acc);
        if (q + 2 < 8)
            ldstage<ISB>(x, xb, wp, arow, (q + 2) * 32 + quad * 8, s0);
        domfma(s1, acc);
    }
}

template <int ISB>
__global__ __launch_bounds__(384, 6) void proj_kernel(
    const void* __restrict__ x,
    const void* __restrict__ w1, const void* __restrict__ w2,
    const void* __restrict__ w3,
    const void* __restrict__ cpw, const void* __restrict__ cw1,
    const void* __restrict__ cw2,
    const void* __restrict__ b1g, const void* __restrict__ b1b,
    const void* __restrict__ b1m, const void* __restrict__ b1v,
    const void* __restrict__ b2g, const void* __restrict__ b2b,
    const void* __restrict__ b2m, const void* __restrict__ b2v,
    unsigned short* __restrict__ y12,
    unsigned short* __restrict__ y3a,
    float* __restrict__ prep)
{
    const int tid = threadIdx.x;

    // prep: 16 blocks x 196 px each (one iteration per thread); block 0 also
    // copies the small weight tensors (prep[0..419] is contiguous CP|W1|W2).
    if (blockIdx.x < 16) {
        if (blockIdx.x == 0) {
            for (int i = tid; i < 420; i += 384) {
                float v;
                if      (i < 4)   v = ldp(cpw, i,        ISB);
                else if (i < 292) v = ldp(cw1, i - 4,    ISB);
                else              v = ldp(cw2, i - 292,  ISB);
                prep[i] = v;
            }
        }
        const int i0 = blockIdx.x * 196;
        if (tid < 196) {
            const int i = i0 + tid;
            float a1 = ldp(b1g, i, ISB) * rsqrtf(ldp(b1v, i, ISB) + 1e-3f);
            float c1 = ldp(b1b, i, ISB) - ldp(b1m, i, ISB) * a1;
            float a2 = ldp(b2g, i, ISB) * rsqrtf(ldp(b2v, i, ISB) + 1e-3f);
            float c2 = ldp(b2b, i, ISB) - ldp(b2m, i, ISB) * a2;
            prep[P_BN + i]          = a1;
            prep[P_BN + HW + i]     = c1;
            prep[P_BN + 2 * HW + i] = a2;
            prep[P_BN + 3 * HW + i] = c2;
        }
    }

    // block = one (n, px0); the 6 waves are the 6 row-tiles.
    const int n   = blockIdx.x / 49;
    const int pt  = blockIdx.x - n * 49;
    const int px0 = pt * 64;                       // 49 * 64 = 3136 exact
    const int rt  = tid >> 6;                      // 0..5, wave-uniform
    const int lane = tid & 63;
    const int col = lane & 15, quad = lane >> 4;

    const void* wp; int ro;
    if      (rt == 0) { wp = w1; ro = 0;  }
    else if (rt == 1) { wp = w2; ro = 0;  }
    else if (rt == 2) { wp = w3; ro = 0;  }
    else if (rt == 3) { wp = w3; ro = 16; }
    else if (rt == 4) { wp = w3; ro = 32; }
    else              { wp = w3; ro = 48; }

    const size_t xb = (size_t)n * 256 * HW + px0 + 4 * col;

    floatx4 acc[4] = {};
    proj_body<ISB>(x, wp, ro + col, xb, quad, acc);

    // D: ch = 16*rt + quad*4 + g, px = px0 + 4*col + tt
    const int chq = quad * 4;
    #pragma unroll
    for (int tt = 0; tt < 4; ++tt) {
        const int px = px0 + 4 * col + tt;
        ushort4v pk;
        #pragma unroll
        for (int g = 0; g < 4; ++g) pk[g] = f2bf(acc[tt][g]);
        if (rt < 2) {
            *(ushort4v*)(y12 + ((size_t)n * HW + px) * 32 + rt * 16 + chq) = pk;
        } else {
            const int k8 = 2 * (rt - 2) + (quad >> 1);
            *(ushort4v*)(y3a + (((size_t)n * 8 + k8) * HW + px) * 8 + (quad & 1) * 4) = pk;
        }
    }
}

// ---------------------------------------------------------------------------
// Fused attention: block = 576 threads (9 waves) = 64 pixels.
// Weights/BN via prep (uniform idx -> s_load). y12/y3a layouts coalesced.
// ---------------------------------------------------------------------------
template <int ISB>
__global__ __launch_bounds__(576) void attn_kernel(
    const unsigned short* __restrict__ y12,
    const unsigned short* __restrict__ y3a,
    const float* __restrict__ prep,
    void* __restrict__ out)
{
    __shared__ float wsm[64 * WS];
    const int tid = threadIdx.x;
    const int blk = blockIdx.x;
    const int n   = blk / 49;
    const int l0  = (blk - n * 49) * 64;

    // ---- phase 1: pre-softmax h2[8] per (pixel, j) ----
    {
        const int j = tid >> 6;            // 0..8, wave-uniform
        const int p = tid & 63;
        const int l = l0 + p;
        const int h = l / 56, w = l - h * 56;
        const int dy = j / 3 - 1, dx = j - (j / 3) * 3 - 1;
        int hh = h + dy; hh = (hh < 0) ? -hh : ((hh > 55) ? 110 - hh : hh);
        int ww = w + dx; ww = (ww < 0) ? -ww : ((ww > 55) ? 110 - ww : ww);
        const int nbr = hh * 56 + ww;

        const float a1 = prep[P_BN + l];
        const float c1 = prep[P_BN + HW + l];
        const float a2 = prep[P_BN + 2 * HW + l];
        const float c2 = prep[P_BN + 3 * HW + l];

        const unsigned short* y1p = y12 + ((size_t)n * HW + l) * 32;
        const unsigned short* y2p = y12 + ((size_t)n * HW + nbr) * 32 + 16;
        float y1f[16], y2f[16];
        unp8(*(const uint4*)y1p, y1f);       unp8(*(const uint4*)(y1p + 8), y1f + 8);
        unp8(*(const uint4*)y2p, y2f);       unp8(*(const uint4*)(y2p + 8), y2f + 8);

        float rel[18];
        #pragma unroll
        for (int c = 0; c < 16; ++c)
            rel[c] = fmaxf(fmaf(y1f[c] - y2f[c], a1, c1), 0.f);
        const float dlw = (float)(w - ww) * (2.0f / 55.0f);
        const float dlh = (float)(h - hh) * (2.0f / 55.0f);
        rel[16] = fmaxf(fmaf(prep[P_CP + 0] * dlw + prep[P_CP + 1] * dlh, a1, c1), 0.f);
        rel[17] = fmaxf(fmaf(prep[P_CP + 2] * dlw + prep[P_CP + 3] * dlh, a1, c1), 0.f);

        float h1[16];
        #pragma unroll
        for (int o = 0; o < 16; ++o) {
            float s = 0.f;
            #pragma unroll
            for (int c = 0; c < 18; ++c)
                s = fmaf(prep[P_W1 + o * 18 + c], rel[c], s);
            h1[o] = fmaxf(fmaf(s, a2, c2), 0.f);
        }
        float h2[8];
        #pragma unroll
        for (int o2 = 0; o2 < 8; ++o2) {
            float s = 0.f;
            #pragma unroll
            for (int o = 0; o < 16; ++o)
                s = fmaf(prep[P_W2 + o2 * 16 + o], h1[o], s);
            h2[o2] = s;
        }
        float* wpt = &wsm[p * WS + j * 8];
        *(floatx4*)wpt       = *(floatx4*)&h2[0];
        *(floatx4*)(wpt + 4) = *(floatx4*)&h2[4];
    }
    __syncthreads();

    // ---- phase 2: softmax over j ----
    if (tid < 512) {
        const int c = tid & 7, p = tid >> 3;
        float v[9];
        #pragma unroll
        for (int j = 0; j < 9; ++j) v[j] = wsm[p * WS + j * 8 + c];
        float m = v[0];
        #pragma unroll
        for (int j = 1; j < 9; ++j) m = fmaxf(m, v[j]);
        float s = 0.f;
        #pragma unroll
        for (int j = 0; j < 9; ++j) { v[j] = __expf(v[j] - m); s += v[j]; }
        const float inv = 1.f / s;
        #pragma unroll
        for (int j = 0; j < 9; ++j) wsm[p * WS + j * 8 + c] = v[j] * inv;
    }
    __syncthreads();

    // ---- phase 3: aggregation, y3a reads 16 B/lane contiguous per wave ----
    if (tid < 512) {
        const int p  = tid & 63;
        const int k8 = tid >> 6;           // wave-uniform channel-group of 8
        const int l = l0 + p;
        const int h = l / 56, w = l - h * 56;
        int nbr[9];
        #pragma unroll
        for (int dy = 0; dy < 3; ++dy)
            #pragma unroll
            for (int dx = 0; dx < 3; ++dx) {
                int hh = h + dy - 1; hh = (hh < 0) ? -hh : ((hh > 55) ? 110 - hh : hh);
                int ww = w + dx - 1; ww = (ww < 0) ? -ww : ((ww > 55) ? 110 - ww : ww);
                nbr[dy * 3 + dx] = hh * 56 + ww;
            }
        const unsigned short* y3b = y3a + ((size_t)n * 8 + k8) * HW * 8;
        float acc8[8];
        #pragma unroll
        for (int k = 0; k < 8; ++k) acc8[k] = 0.f;
        #pragma unroll
        for (int j = 0; j < 9; ++j) {
            uint4 u = *(const uint4*)(y3b + (size_t)nbr[j] * 8);
            float yv[8];
            unp8(u, yv);
            const float* wpt = &wsm[p * WS + j * 8];
            #pragma unroll
            for (int k = 0; k < 8; ++k)
                acc8[k] = fmaf(wpt[k], yv[k], acc8[k]);
        }
        const size_t obase = ((size_t)n * 64 + k8 * 8) * HW + l;
        #pragma unroll
        for (int k = 0; k < 8; ++k) {
            if (ISB) ((unsigned short*)out)[obase + (size_t)k * HW] = f2bf(acc8[k]);
            else     ((float*)out)[obase + (size_t)k * HW]          = acc8[k];
        }
    }
}

extern "C" void kernel_launch(void* const* d_in, const int* in_sizes, int n_in,
                              void* d_out, int out_size, void* d_ws, size_t ws_size,
                              hipStream_t stream)
{
    const size_t y12B = (size_t)16 * HW * 32 * 2;      // 3,211,264 B
    const size_t y3aB = (size_t)16 * 8 * HW * 8 * 2;   // 6,422,528 B

    unsigned short* y12 = (unsigned short*)d_ws;
    unsigned short* y3a = (unsigned short*)((char*)d_ws + y12B);
    float* prep = (float*)((char*)d_ws + y12B + y3aB);

    // dtype detect on HOST: bn1_var is [3136] -> 6272 B bf16, 12544 B fp32.
    const int isb = (in_sizes[10] == HW * 2);

    if (isb) {
        proj_kernel<1><<<dim3(784), dim3(384), 0, stream>>>(
            d_in[0], d_in[1], d_in[2], d_in[3],
            d_in[4], d_in[5], d_in[6],
            d_in[7], d_in[8], d_in[9], d_in[10],
            d_in[11], d_in[12], d_in[13], d_in[14],
            y12, y3a, prep);
        attn_kernel<1><<<dim3(784), dim3(576), 0, stream>>>(y12, y3a, prep, d_out);
    } else {
        proj_kernel<0><<<dim3(784), dim3(384), 0, stream>>>(
            d_in[0], d_in[1], d_in[2], d_in[3],
            d_in[4], d_in[5], d_in[6],
            d_in[7], d_in[8], d_in[9], d_in[10],
            d_in[11], d_in[12], d_in[13], d_in[14],
            y12, y3a, prep);
        attn_kernel<0><<<dim3(784), dim3(576), 0, stream>>>(y12, y3a, prep, d_out);
    }
}

// Round 5
// 149.816 us; speedup vs baseline: 1.1234x; 1.1234x over previous
//
#include <hip/hip_runtime.h>

typedef short bf16x8 __attribute__((ext_vector_type(8)));
typedef float floatx4 __attribute__((ext_vector_type(4)));
typedef unsigned short ushort4v __attribute__((ext_vector_type(4)));
typedef unsigned int uintx4 __attribute__((ext_vector_type(4)));
typedef unsigned int uintx2 __attribute__((ext_vector_type(2)));

#define HW 3136
#define WS 100   // attn LDS stride (floats) per pixel

// prep layout (floats)
#define P_CP   0
#define P_W1   4      // 288
#define P_W2   292    // 128
#define P_BN   424    // a1[HW], c1[HW], a2[HW], c2[HW]
#define PREP_FLOATS (424 + 4 * HW)

// ---- bf16 bit helpers (RNE) ----
__device__ __forceinline__ unsigned short f2bf(float f) {
    unsigned int u = __float_as_uint(f);
    unsigned int r = (u + 0x7FFFu + ((u >> 16) & 1u)) >> 16;
    return (unsigned short)r;
}
__device__ __forceinline__ float bf2f(unsigned short u) {
    return __uint_as_float(((unsigned int)u) << 16);
}
__device__ __forceinline__ void unp8(uint4 u, float* o) {
    o[0] = bf2f((unsigned short)(u.x & 0xFFFFu)); o[1] = bf2f((unsigned short)(u.x >> 16));
    o[2] = bf2f((unsigned short)(u.y & 0xFFFFu)); o[3] = bf2f((unsigned short)(u.y >> 16));
    o[4] = bf2f((unsigned short)(u.z & 0xFFFFu)); o[5] = bf2f((unsigned short)(u.z >> 16));
    o[6] = bf2f((unsigned short)(u.w & 0xFFFFu)); o[7] = bf2f((unsigned short)(u.w >> 16));
}
__device__ __forceinline__ float ldp(const void* p, int i, int isb) {
    return isb ? bf2f(((const unsigned short*)p)[i]) : ((const float*)p)[i];
}

// ---------------------------------------------------------------------------
// proj: wave = 64 px x 16 rows over K=256. Block = 384 threads = 6 waves =
// ALL SIX row-tiles of ONE (n, px0) -> x-slice read 6x from one L2
// (round-3 result: FETCH 115 -> 37 MB, keep this).
// __launch_bounds__(384, 3): round-2/3 post-mortem found min-waves>=5
// starved the allocator (VGPR 88 -> 40/48), spilling the pipeline Stage
// arrays to scratch: +22 MB WRITE_SIZE (9.6 -> 32), spill re-reads, and a
// serialized inner loop (55 us vs round-1's <=41.5). Body needs ~70-90
// VGPRs; cap 170 leaves it unconstrained -> expect ~88 regs, 5 waves/SIMD,
// 3 blocks/CU, 768/784 blocks co-resident.
// (Round-4 submission of this exact source hit an infra failure --
// "container failed twice", no compile/test signal -- resubmitting as-is.)
// BN prep spread over blocks 0..15. dtype resolved host-side via in_sizes.
// Outputs: y12[n][px][32ch] and y3a[n][k8][px][8ch] (attn-coalesced).
// ---------------------------------------------------------------------------
struct __align__(16) Stage { unsigned int b[16]; bf16x8 a; };

template <int ISB>
__device__ __forceinline__ void ldstage(const void* x, size_t xb,
                                        const void* wp, int arow, int ch, Stage& s)
{
    if (ISB) {
        const unsigned short* p = (const unsigned short*)x + xb + (size_t)ch * HW;
        #pragma unroll
        for (int j = 0; j < 8; ++j)
            *(uintx2*)&s.b[2 * j] = *(const uintx2*)(p + (size_t)j * HW);
        s.a = *(const bf16x8*)((const unsigned short*)wp + arow * 256 + ch);
    } else {
        const float* p = (const float*)x + xb + (size_t)ch * HW;
        #pragma unroll
        for (int j = 0; j < 8; ++j) {
            floatx4 f = *(const floatx4*)(p + (size_t)j * HW);
            s.b[2 * j + 0] = (unsigned)f2bf(f[0]) | ((unsigned)f2bf(f[1]) << 16);
            s.b[2 * j + 1] = (unsigned)f2bf(f[2]) | ((unsigned)f2bf(f[3]) << 16);
        }
        const float* fp = (const float*)wp + arow * 256 + ch;
        bf16x8 a;
        #pragma unroll
        for (int j = 0; j < 8; ++j) a[j] = (short)f2bf(fp[j]);
        s.a = a;
    }
}

__device__ __forceinline__ void domfma(const Stage& s, floatx4 (&acc)[4])
{
    #pragma unroll
    for (int t = 0; t < 4; ++t) {
        const int wi = t >> 1;
        uintx4 uv;
        #pragma unroll
        for (int d = 0; d < 4; ++d) {
            const unsigned lo = s.b[2 * (2 * d) + wi];
            const unsigned hi = s.b[2 * (2 * d + 1) + wi];
            const unsigned v = (t & 1) ? ((lo >> 16) | (hi & 0xFFFF0000u))
                                       : ((lo & 0xFFFFu) | (hi << 16));
            uv[d] = v;
        }
        bf16x8 B = __builtin_bit_cast(bf16x8, uv);
        acc[t] = __builtin_amdgcn_mfma_f32_16x16x32_bf16(s.a, B, acc[t], 0, 0, 0);
    }
}

template <int ISB>
__device__ void proj_body(const void* x, const void* wp, int arow,
                          size_t xb, int quad, floatx4 (&acc)[4])
{
    Stage s0, s1;
    ldstage<ISB>(x, xb, wp, arow, quad * 8, s0);
    #pragma unroll
    for (int q = 0; q < 8; q += 2) {
        ldstage<ISB>(x, xb, wp, arow, (q + 1) * 32 + quad * 8, s1);
        domfma(s0, acc);
        if (q + 2 < 8)
            ldstage<ISB>(x, xb, wp, arow, (q + 2) * 32 + quad * 8, s0);
        domfma(s1, acc);
    }
}

template <int ISB>
__global__ __launch_bounds__(384, 3) void proj_kernel(
    const void* __restrict__ x,
    const void* __restrict__ w1, const void* __restrict__ w2,
    const void* __restrict__ w3,
    const void* __restrict__ cpw, const void* __restrict__ cw1,
    const void* __restrict__ cw2,
    const void* __restrict__ b1g, const void* __restrict__ b1b,
    const void* __restrict__ b1m, const void* __restrict__ b1v,
    const void* __restrict__ b2g, const void* __restrict__ b2b,
    const void* __restrict__ b2m, const void* __restrict__ b2v,
    unsigned short* __restrict__ y12,
    unsigned short* __restrict__ y3a,
    float* __restrict__ prep)
{
    const int tid = threadIdx.x;

    // prep: 16 blocks x 196 px each (one iteration per thread); block 0 also
    // copies the small weight tensors (prep[0..419] is contiguous CP|W1|W2).
    if (blockIdx.x < 16) {
        if (blockIdx.x == 0) {
            for (int i = tid; i < 420; i += 384) {
                float v;
                if      (i < 4)   v = ldp(cpw, i,        ISB);
                else if (i < 292) v = ldp(cw1, i - 4,    ISB);
                else              v = ldp(cw2, i - 292,  ISB);
                prep[i] = v;
            }
        }
        const int i0 = blockIdx.x * 196;
        if (tid < 196) {
            const int i = i0 + tid;
            float a1 = ldp(b1g, i, ISB) * rsqrtf(ldp(b1v, i, ISB) + 1e-3f);
            float c1 = ldp(b1b, i, ISB) - ldp(b1m, i, ISB) * a1;
            float a2 = ldp(b2g, i, ISB) * rsqrtf(ldp(b2v, i, ISB) + 1e-3f);
            float c2 = ldp(b2b, i, ISB) - ldp(b2m, i, ISB) * a2;
            prep[P_BN + i]          = a1;
            prep[P_BN + HW + i]     = c1;
            prep[P_BN + 2 * HW + i] = a2;
            prep[P_BN + 3 * HW + i] = c2;
        }
    }

    // block = one (n, px0); the 6 waves are the 6 row-tiles.
    const int n   = blockIdx.x / 49;
    const int pt  = blockIdx.x - n * 49;
    const int px0 = pt * 64;                       // 49 * 64 = 3136 exact
    const int rt  = tid >> 6;                      // 0..5, wave-uniform
    const int lane = tid & 63;
    const int col = lane & 15, quad = lane >> 4;

    const void* wp; int ro;
    if      (rt == 0) { wp = w1; ro = 0;  }
    else if (rt == 1) { wp = w2; ro = 0;  }
    else if (rt == 2) { wp = w3; ro = 0;  }
    else if (rt == 3) { wp = w3; ro = 16; }
    else if (rt == 4) { wp = w3; ro = 32; }
    else              { wp = w3; ro = 48; }

    const size_t xb = (size_t)n * 256 * HW + px0 + 4 * col;

    floatx4 acc[4] = {};
    proj_body<ISB>(x, wp, ro + col, xb, quad, acc);

    // D: ch = 16*rt + quad*4 + g, px = px0 + 4*col + tt
    const int chq = quad * 4;
    #pragma unroll
    for (int tt = 0; tt < 4; ++tt) {
        const int px = px0 + 4 * col + tt;
        ushort4v pk;
        #pragma unroll
        for (int g = 0; g < 4; ++g) pk[g] = f2bf(acc[tt][g]);
        if (rt < 2) {
            *(ushort4v*)(y12 + ((size_t)n * HW + px) * 32 + rt * 16 + chq) = pk;
        } else {
            const int k8 = 2 * (rt - 2) + (quad >> 1);
            *(ushort4v*)(y3a + (((size_t)n * 8 + k8) * HW + px) * 8 + (quad & 1) * 4) = pk;
        }
    }
}

// ---------------------------------------------------------------------------
// Fused attention: block = 576 threads (9 waves) = 64 pixels.
// Weights/BN via prep (uniform idx -> s_load). y12/y3a layouts coalesced.
// ---------------------------------------------------------------------------
template <int ISB>
__global__ __launch_bounds__(576) void attn_kernel(
    const unsigned short* __restrict__ y12,
    const unsigned short* __restrict__ y3a,
    const float* __restrict__ prep,
    void* __restrict__ out)
{
    __shared__ float wsm[64 * WS];
    const int tid = threadIdx.x;
    const int blk = blockIdx.x;
    const int n   = blk / 49;
    const int l0  = (blk - n * 49) * 64;

    // ---- phase 1: pre-softmax h2[8] per (pixel, j) ----
    {
        const int j = tid >> 6;            // 0..8, wave-uniform
        const int p = tid & 63;
        const int l = l0 + p;
        const int h = l / 56, w = l - h * 56;
        const int dy = j / 3 - 1, dx = j - (j / 3) * 3 - 1;
        int hh = h + dy; hh = (hh < 0) ? -hh : ((hh > 55) ? 110 - hh : hh);
        int ww = w + dx; ww = (ww < 0) ? -ww : ((ww > 55) ? 110 - ww : ww);
        const int nbr = hh * 56 + ww;

        const float a1 = prep[P_BN + l];
        const float c1 = prep[P_BN + HW + l];
        const float a2 = prep[P_BN + 2 * HW + l];
        const float c2 = prep[P_BN + 3 * HW + l];

        const unsigned short* y1p = y12 + ((size_t)n * HW + l) * 32;
        const unsigned short* y2p = y12 + ((size_t)n * HW + nbr) * 32 + 16;
        float y1f[16], y2f[16];
        unp8(*(const uint4*)y1p, y1f);       unp8(*(const uint4*)(y1p + 8), y1f + 8);
        unp8(*(const uint4*)y2p, y2f);       unp8(*(const uint4*)(y2p + 8), y2f + 8);

        float rel[18];
        #pragma unroll
        for (int c = 0; c < 16; ++c)
            rel[c] = fmaxf(fmaf(y1f[c] - y2f[c], a1, c1), 0.f);
        const float dlw = (float)(w - ww) * (2.0f / 55.0f);
        const float dlh = (float)(h - hh) * (2.0f / 55.0f);
        rel[16] = fmaxf(fmaf(prep[P_CP + 0] * dlw + prep[P_CP + 1] * dlh, a1, c1), 0.f);
        rel[17] = fmaxf(fmaf(prep[P_CP + 2] * dlw + prep[P_CP + 3] * dlh, a1, c1), 0.f);

        float h1[16];
        #pragma unroll
        for (int o = 0; o < 16; ++o) {
            float s = 0.f;
            #pragma unroll
            for (int c = 0; c < 18; ++c)
                s = fmaf(prep[P_W1 + o * 18 + c], rel[c], s);
            h1[o] = fmaxf(fmaf(s, a2, c2), 0.f);
        }
        float h2[8];
        #pragma unroll
        for (int o2 = 0; o2 < 8; ++o2) {
            float s = 0.f;
            #pragma unroll
            for (int o = 0; o < 16; ++o)
                s = fmaf(prep[P_W2 + o2 * 16 + o], h1[o], s);
            h2[o2] = s;
        }
        float* wpt = &wsm[p * WS + j * 8];
        *(floatx4*)wpt       = *(floatx4*)&h2[0];
        *(floatx4*)(wpt + 4) = *(floatx4*)&h2[4];
    }
    __syncthreads();

    // ---- phase 2: softmax over j ----
    if (tid < 512) {
        const int c = tid & 7, p = tid >> 3;
        float v[9];
        #pragma unroll
        for (int j = 0; j < 9; ++j) v[j] = wsm[p * WS + j * 8 + c];
        float m = v[0];
        #pragma unroll
        for (int j = 1; j < 9; ++j) m = fmaxf(m, v[j]);
        float s = 0.f;
        #pragma unroll
        for (int j = 0; j < 9; ++j) { v[j] = __expf(v[j] - m); s += v[j]; }
        const float inv = 1.f / s;
        #pragma unroll
        for (int j = 0; j < 9; ++j) wsm[p * WS + j * 8 + c] = v[j] * inv;
    }
    __syncthreads();

    // ---- phase 3: aggregation, y3a reads 16 B/lane contiguous per wave ----
    if (tid < 512) {
        const int p  = tid & 63;
        const int k8 = tid >> 6;           // wave-uniform channel-group of 8
        const int l = l0 + p;
        const int h = l / 56, w = l - h * 56;
        int nbr[9];
        #pragma unroll
        for (int dy = 0; dy < 3; ++dy)
            #pragma unroll
            for (int dx = 0; dx < 3; ++dx) {
                int hh = h + dy - 1; hh = (hh < 0) ? -hh : ((hh > 55) ? 110 - hh : hh);
                int ww = w + dx - 1; ww = (ww < 0) ? -ww : ((ww > 55) ? 110 - ww : ww);
                nbr[dy * 3 + dx] = hh * 56 + ww;
            }
        const unsigned short* y3b = y3a + ((size_t)n * 8 + k8) * HW * 8;
        float acc8[8];
        #pragma unroll
        for (int k = 0; k < 8; ++k) acc8[k] = 0.f;
        #pragma unroll
        for (int j = 0; j < 9; ++j) {
            uint4 u = *(const uint4*)(y3b + (size_t)nbr[j] * 8);
            float yv[8];
            unp8(u, yv);
            const float* wpt = &wsm[p * WS + j * 8];
            #pragma unroll
            for (int k = 0; k < 8; ++k)
                acc8[k] = fmaf(wpt[k], yv[k], acc8[k]);
        }
        const size_t obase = ((size_t)n * 64 + k8 * 8) * HW + l;
        #pragma unroll
        for (int k = 0; k < 8; ++k) {
            if (ISB) ((unsigned short*)out)[obase + (size_t)k * HW] = f2bf(acc8[k]);
            else     ((float*)out)[obase + (size_t)k * HW]          = acc8[k];
        }
    }
}

extern "C" void kernel_launch(void* const* d_in, const int* in_sizes, int n_in,
                              void* d_out, int out_size, void* d_ws, size_t ws_size,
                              hipStream_t stream)
{
    const size_t y12B = (size_t)16 * HW * 32 * 2;      // 3,211,264 B
    const size_t y3aB = (size_t)16 * 8 * HW * 8 * 2;   // 6,422,528 B

    unsigned short* y12 = (unsigned short*)d_ws;
    unsigned short* y3a = (unsigned short*)((char*)d_ws + y12B);
    float* prep = (float*)((char*)d_ws + y12B + y3aB);

    // dtype detect on HOST: bn1_var is [3136] -> 6272 B bf16, 12544 B fp32.
    const int isb = (in_sizes[10] == HW * 2);

    if (isb) {
        proj_kernel<1><<<dim3(784), dim3(384), 0, stream>>>(
            d_in[0], d_in[1], d_in[2], d_in[3],
            d_in[4], d_in[5], d_in[6],
            d_in[7], d_in[8], d_in[9], d_in[10],
            d_in[11], d_in[12], d_in[13], d_in[14],
            y12, y3a, prep);
        attn_kernel<1><<<dim3(784), dim3(576), 0, stream>>>(y12, y3a, prep, d_out);
    } else {
        proj_kernel<0><<<dim3(784), dim3(384), 0, stream>>>(
            d_in[0], d_in[1], d_in[2], d_in[3],
            d_in[4], d_in[5], d_in[6],
            d_in[7], d_in[8], d_in[9], d_in[10],
            d_in[11], d_in[12], d_in[13], d_in[14],
            y12, y3a, prep);
        attn_kernel<0><<<dim3(784), dim3(576), 0, stream>>>(y12, y3a, prep, d_out);
    }
}